// Round 4
// baseline (404.537 us; speedup 1.0000x reference)
//
#include <hip/hip_runtime.h>
#include <math.h>

// Problem constants (from reference: SHAPES fixed, EMB=HID=256, H=8, L=4, P=4)
#define NB    2
#define NQ    11253          // I == N == sum(h*w) = 92^2+46^2+23^2+12^2
#define NEMB  256
#define NHID  256
#define NH    8
#define NCP   32             // HID / H
#define MROWS (NB * NQ)      // 22506

// Level geometry (hardcoded from SHAPES); starts: 0, 8464, 10580, 11109
__device__ __constant__ int LVL_H[4]     = {92, 46, 23, 12};
__device__ __constant__ int LVL_W[4]     = {92, 46, 23, 12};
__device__ __constant__ int LVL_START[4] = {0, 8464, 10580, 11109};

// ---------------------------------------------------------------------------
// Tiled fp32 GEMM with bias: C[M,N] = A[M,K] @ B[K,N] + bias[N]
// BM=128, BN=64, BK=16, 256 threads, 8x4 micro-tile per thread.
// Requires: N % 64 == 0, K % 16 == 0 (true for 256/384).
// ---------------------------------------------------------------------------
__global__ __launch_bounds__(256) void gemm_bias(
    const float* __restrict__ A, const float* __restrict__ B,
    const float* __restrict__ bias, float* __restrict__ C,
    int M, int N, int K)
{
    __shared__ float As[16][128];   // [k][m]
    __shared__ float Bs[16][64];    // [k][n]

    const int t  = threadIdx.x;
    const int tx = t & 15;          // col group (4 cols)
    const int ty = t >> 4;          // row group (8 rows)
    const int blockRow = blockIdx.x * 128;
    const int blockCol = blockIdx.y * 64;

    // A-tile load mapping: 128 rows x 16 k; 2 float4 per thread
    const int lr = t >> 1;            // row 0..127
    const int lk = (t & 1) * 8;       // k offset 0 or 8
    const int gr = blockRow + lr;
    // B-tile load mapping: 16 k x 64 cols; 1 float4 per thread
    const int bk = t >> 4;            // 0..15
    const int bc = (t & 15) << 2;     // 0..60

    float acc[8][4] = {};

    for (int k0 = 0; k0 < K; k0 += 16) {
        float4 a0 = make_float4(0.f, 0.f, 0.f, 0.f);
        float4 a1 = make_float4(0.f, 0.f, 0.f, 0.f);
        if (gr < M) {
            const float* ap = A + (size_t)gr * K + k0 + lk;
            a0 = *(const float4*)(ap);
            a1 = *(const float4*)(ap + 4);
        }
        As[lk + 0][lr] = a0.x;  As[lk + 1][lr] = a0.y;
        As[lk + 2][lr] = a0.z;  As[lk + 3][lr] = a0.w;
        As[lk + 4][lr] = a1.x;  As[lk + 5][lr] = a1.y;
        As[lk + 6][lr] = a1.z;  As[lk + 7][lr] = a1.w;

        *(float4*)(&Bs[bk][bc]) =
            *(const float4*)(B + (size_t)(k0 + bk) * N + blockCol + bc);

        __syncthreads();
        #pragma unroll
        for (int kk = 0; kk < 16; ++kk) {
            float a[8], b[4];
            *(float4*)(&a[0]) = *(const float4*)(&As[kk][ty * 8 + 0]);
            *(float4*)(&a[4]) = *(const float4*)(&As[kk][ty * 8 + 4]);
            *(float4*)(&b[0]) = *(const float4*)(&Bs[kk][tx * 4]);
            #pragma unroll
            for (int i = 0; i < 8; ++i)
                #pragma unroll
                for (int j = 0; j < 4; ++j)
                    acc[i][j] = fmaf(a[i], b[j], acc[i][j]);
        }
        __syncthreads();
    }

    const int colBase = blockCol + (tx << 2);
    const float4 bia = *(const float4*)(bias + colBase);
    #pragma unroll
    for (int i = 0; i < 8; ++i) {
        int row = blockRow + ty * 8 + i;
        if (row >= M) continue;
        float4 o;
        o.x = acc[i][0] + bia.x;
        o.y = acc[i][1] + bia.y;
        o.z = acc[i][2] + bia.z;
        o.w = acc[i][3] + bia.w;
        *(float4*)(C + (size_t)row * N + colBase) = o;
    }
}

// ---------------------------------------------------------------------------
// Fused MSDA: per (b,n,h) group of 32 lanes (lane = channel cp):
//   1. softmax over 16 (l,p) scores from qp (redundant per lane, broadcast loads)
//   2. sampling points = ref + offset
//   3. out[b,n,h,cp] = sum_{l,p} aw * bilinear(img_p, sp)
// img_p layout: (B, I, H, CP) -> ((b*NQ+i)*NH + h)*NCP + cp
// qp layout: (B,N, H*L*P*3) with ((h*L+l)*P+p)*3 + {x,y,score}
// ---------------------------------------------------------------------------
__global__ __launch_bounds__(256) void msda_kernel(
    const float* __restrict__ img_p, const float* __restrict__ qp,
    const float* __restrict__ refp, float* __restrict__ out)
{
    const int lane = threadIdx.x & 31;   // cp
    const int g    = threadIdx.x >> 5;   // group within block (8 groups)
    const int idx  = blockIdx.x * 8 + g; // (b*NQ+n)*NH + h
    if (idx >= NB * NQ * NH) return;
    const int h  = idx & 7;
    const int bn = idx >> 3;
    const int b  = bn / NQ;

    const float* q  = qp + (size_t)bn * 384 + h * 48;
    const float rx = refp[bn * 2 + 0];
    const float ry = refp[bn * 2 + 1];

    // softmax over the 16 (l,p) scores — redundant per lane; same-address
    // loads broadcast from cache; __expf = hardware v_exp_f32 path.
    float sc[16];
    float m = -1e30f;
    #pragma unroll
    for (int s = 0; s < 16; ++s) { sc[s] = q[s * 3 + 2]; m = fmaxf(m, sc[s]); }
    float sum = 0.f;
    #pragma unroll
    for (int s = 0; s < 16; ++s) { sc[s] = __expf(sc[s] - m); sum += sc[s]; }
    const float inv = 1.f / sum;

    float acc = 0.f;
    #pragma unroll
    for (int l = 0; l < 4; ++l) {
        const int hh = LVL_H[l], ww = LVL_W[l], st = LVL_START[l];
        const float* base = img_p + (((size_t)b * NQ + st) * NH + h) * NCP + lane;
        #pragma unroll
        for (int p = 0; p < 4; ++p) {
            const int s = l * 4 + p;
            const float w = sc[s] * inv;
            float x = (rx + q[s * 3 + 0]) * (float)(ww - 1);
            float y = (ry + q[s * 3 + 1]) * (float)(hh - 1);
            x = fminf(fmaxf(x, 0.f), (float)(ww - 1));
            y = fminf(fmaxf(y, 0.f), (float)(hh - 1));
            const float x0f = floorf(x), y0f = floorf(y);
            const int x0 = (int)x0f, y0 = (int)y0f;
            const float wx = x - x0f, wy = y - y0f;
            const int x1 = min(x0 + 1, ww - 1);
            const int y1 = min(y0 + 1, hh - 1);

            const float v00 = base[((size_t)(y0 * ww + x0)) * (NH * NCP)];
            const float v01 = base[((size_t)(y0 * ww + x1)) * (NH * NCP)];
            const float v10 = base[((size_t)(y1 * ww + x0)) * (NH * NCP)];
            const float v11 = base[((size_t)(y1 * ww + x1)) * (NH * NCP)];

            const float v = v00 * (1.f - wy) * (1.f - wx)
                          + v01 * (1.f - wy) * wx
                          + v10 * wy * (1.f - wx)
                          + v11 * wy * wx;
            acc = fmaf(w, v, acc);
        }
    }
    // out layout: (B, N, H, CP) == (B, N, HID)
    out[(size_t)bn * NHID + h * NCP + lane] = acc;
}

// ---------------------------------------------------------------------------
extern "C" void kernel_launch(void* const* d_in, const int* in_sizes, int n_in,
                              void* d_out, int out_size, void* d_ws, size_t ws_size,
                              hipStream_t stream) {
    const float* img     = (const float*)d_in[0];
    // d_in[1] = shapes (int32) -- hardcoded
    const float* queries = (const float*)d_in[2];
    const float* refp    = (const float*)d_in[3];
    const float* W_img   = (const float*)d_in[4];
    const float* b_img   = (const float*)d_in[5];
    const float* W_q     = (const float*)d_in[6];
    const float* b_q     = (const float*)d_in[7];
    const float* W_out   = (const float*)d_in[8];
    const float* b_out   = (const float*)d_in[9];
    float* out = (float*)d_out;

    // workspace layout (floats): img_p 5.76M | qp 8.64M | msda_out 5.76M
    // total 80.6 MB
    float* ws = (float*)d_ws;
    float* img_p    = ws;                             // MROWS*256
    float* qp       = img_p + (size_t)MROWS * NHID;   // MROWS*384
    float* msda_out = qp + (size_t)MROWS * 384;       // MROWS*256

    // 1. img_p = img @ W_img + b_img   (22506 x 256, K=256)
    {
        dim3 grid((MROWS + 127) / 128, NHID / 64);
        gemm_bias<<<grid, 256, 0, stream>>>(img, W_img, b_img, img_p, MROWS, NHID, NEMB);
    }
    // 2. qp = queries @ W_q + b_q      (22506 x 384, K=256)
    {
        dim3 grid((MROWS + 127) / 128, 384 / 64);
        gemm_bias<<<grid, 256, 0, stream>>>(queries, W_q, b_q, qp, MROWS, 384, NEMB);
    }
    // 3. fused softmax + sampling + weighted sum
    {
        int groups = NB * NQ * NH;                 // 180,048
        msda_kernel<<<(groups + 7) / 8, 256, 0, stream>>>(img_p, qp, refp, msda_out);
    }
    // 4. out = msda_out @ W_out + b_out (22506 x 256, K=256)
    {
        dim3 grid((MROWS + 127) / 128, NEMB / 64);
        gemm_bias<<<grid, 256, 0, stream>>>(msda_out, W_out, b_out, out, MROWS, NEMB, NHID);
    }
}

// Round 10
// 239.608 us; speedup vs baseline: 1.6883x; 1.6883x over previous
//
#include <hip/hip_runtime.h>
#include <math.h>

// Problem constants (SHAPES fixed; EMB=HID=256, H=8, L=4, P=4)
#define NB    2
#define NQ    11253          // I == N == 92^2+46^2+23^2+12^2
#define NEMB  256
#define NHID  256
#define NH    8
#define NCP   32             // HID / H
#define MROWS (NB * NQ)      // 22506
#define NGRP  (NB * NQ * NH) // 180048

// Level geometry; starts: 0, 8464, 10580, 11109
__device__ __constant__ int LVL_H[4]     = {92, 46, 23, 12};
__device__ __constant__ int LVL_W[4]     = {92, 46, 23, 12};
__device__ __constant__ int LVL_START[4] = {0, 8464, 10580, 11109};

typedef float  f32x4  __attribute__((ext_vector_type(4)));
typedef __bf16 bf16x8 __attribute__((ext_vector_type(8)));
typedef short  s16x8  __attribute__((ext_vector_type(8)));  // MFMA operand view

// ---------------------------------------------------------------------------
// bf16-split MFMA GEMM: C[M,N] = A[M,K]@B[K,N] + bias, fp32 in/out.
// 3-term split: a=hi+lo (bf16); a*b ~= hi*hi + hi*lo + lo*hi (rel err ~2^-16).
// Tile BM=128 x BN=128 x BK=32; 256 threads = 4 waves (2x2 of 64x64);
// per wave 4x4 frags of v_mfma_f32_16x16x32_bf16.
// Fragment maps (guide m89/m91 verified): A: row=lane&15, k=(lane>>4)*8+i;
// B: col=lane&15, k=(lane>>4)*8+i; D: col=lane&15, row=(lane>>4)*4+reg.
// LDS k-stride padded to 40 (80B) -> frag ds_read_b128 spreads banks.
// ---------------------------------------------------------------------------
#define BM 128
#define BN 128
#define BK 32
#define LDK 40

__global__ __launch_bounds__(256) void gemm_mfma_split(
    const float* __restrict__ A, const float* __restrict__ B,
    const float* __restrict__ bias, float* __restrict__ C,
    int M, int N, int K)
{
    __shared__ __bf16 Ah[BM * LDK];
    __shared__ __bf16 Al[BM * LDK];
    __shared__ __bf16 Bh[BN * LDK];
    __shared__ __bf16 Bl[BN * LDK];

    const int t    = threadIdx.x;
    const int brow = blockIdx.x * BM;
    const int bcol = blockIdx.y * BN;
    const int wave = t >> 6;
    const int lane = t & 63;
    const int wr   = (wave >> 1) * 64;
    const int wc   = (wave & 1) * 64;
    const int l15  = lane & 15;
    const int l4   = lane >> 4;

    f32x4 acc[4][4] = {};

    // A staging: thread t loads row (t>>1), k = (t&1)*16 .. +15 (4 float4)
    const int ar = t >> 1;
    const int ak = (t & 1) * 16;
    // B staging: thread t loads cols (t&63)*2, +1; k = (t>>6)*8 .. +7
    const int bc2 = (t & 63) * 2;
    const int bk8 = (t >> 6) * 8;

    for (int k0 = 0; k0 < K; k0 += BK) {
        // ---- stage A (fp32 -> hi/lo bf16)
        {
            float va[16];
            const int grow = brow + ar;
            if (grow < M) {
                const float* ap = A + (size_t)grow * K + k0 + ak;
                *(float4*)&va[0]  = *(const float4*)(ap + 0);
                *(float4*)&va[4]  = *(const float4*)(ap + 4);
                *(float4*)&va[8]  = *(const float4*)(ap + 8);
                *(float4*)&va[12] = *(const float4*)(ap + 12);
            } else {
                #pragma unroll
                for (int i = 0; i < 16; ++i) va[i] = 0.f;
            }
            bf16x8 h0, h1, l0, l1;
            #pragma unroll
            for (int i = 0; i < 8; ++i) {
                __bf16 h = (__bf16)va[i];
                h0[i] = h;  l0[i] = (__bf16)(va[i] - (float)h);
            }
            #pragma unroll
            for (int i = 0; i < 8; ++i) {
                __bf16 h = (__bf16)va[8 + i];
                h1[i] = h;  l1[i] = (__bf16)(va[8 + i] - (float)h);
            }
            *(bf16x8*)&Ah[ar * LDK + ak]     = h0;
            *(bf16x8*)&Ah[ar * LDK + ak + 8] = h1;
            *(bf16x8*)&Al[ar * LDK + ak]     = l0;
            *(bf16x8*)&Al[ar * LDK + ak + 8] = l1;
        }
        // ---- stage B (fp32 [K][N] -> LDS [col][k] hi/lo)
        {
            bf16x8 h0, h1, l0, l1;
            #pragma unroll
            for (int j = 0; j < 8; ++j) {
                float2 v = *(const float2*)(B + (size_t)(k0 + bk8 + j) * N + bcol + bc2);
                __bf16 hx = (__bf16)v.x;
                __bf16 hy = (__bf16)v.y;
                h0[j] = hx;  l0[j] = (__bf16)(v.x - (float)hx);
                h1[j] = hy;  l1[j] = (__bf16)(v.y - (float)hy);
            }
            *(bf16x8*)&Bh[(bc2 + 0) * LDK + bk8] = h0;
            *(bf16x8*)&Bh[(bc2 + 1) * LDK + bk8] = h1;
            *(bf16x8*)&Bl[(bc2 + 0) * LDK + bk8] = l0;
            *(bf16x8*)&Bl[(bc2 + 1) * LDK + bk8] = l1;
        }
        __syncthreads();

        // ---- fragments (read LDS as short8 = env's MFMA operand type) + MFMA
        s16x8 a_h[4], a_l[4], b_h[4], b_l[4];
        #pragma unroll
        for (int mi = 0; mi < 4; ++mi) {
            int off = (wr + mi * 16 + l15) * LDK + l4 * 8;
            a_h[mi] = *(s16x8*)&Ah[off];
            a_l[mi] = *(s16x8*)&Al[off];
        }
        #pragma unroll
        for (int ni = 0; ni < 4; ++ni) {
            int off = (wc + ni * 16 + l15) * LDK + l4 * 8;
            b_h[ni] = *(s16x8*)&Bh[off];
            b_l[ni] = *(s16x8*)&Bl[off];
        }
        #pragma unroll
        for (int mi = 0; mi < 4; ++mi)
            #pragma unroll
            for (int ni = 0; ni < 4; ++ni) {
                acc[mi][ni] = __builtin_amdgcn_mfma_f32_16x16x32_bf16(a_h[mi], b_h[ni], acc[mi][ni], 0, 0, 0);
                acc[mi][ni] = __builtin_amdgcn_mfma_f32_16x16x32_bf16(a_h[mi], b_l[ni], acc[mi][ni], 0, 0, 0);
                acc[mi][ni] = __builtin_amdgcn_mfma_f32_16x16x32_bf16(a_l[mi], b_h[ni], acc[mi][ni], 0, 0, 0);
            }
        __syncthreads();
    }

    // ---- epilogue: D mapping col=lane&15, row=(lane>>4)*4+reg
    #pragma unroll
    for (int ni = 0; ni < 4; ++ni) {
        const int col = bcol + wc + ni * 16 + l15;
        const float bv = bias[col];
        #pragma unroll
        for (int mi = 0; mi < 4; ++mi) {
            #pragma unroll
            for (int j = 0; j < 4; ++j) {
                int row = brow + wr + mi * 16 + l4 * 4 + j;
                if (row < M) C[(size_t)row * N + col] = acc[mi][ni][j] + bv;
            }
        }
    }
}

// ---------------------------------------------------------------------------
// Fused MSDA, 8 lanes per (b,n,h), lane = 4 channels (float4 gathers).
// Producer: lane t3 computes params for samples s=t3, t3+8 (softmax via
// 3-step shfl_xor width 8), publishes {o00_bytes, dx_bytes, dy_bytes,
// w00,w01,w10,w11} to LDS [16][32][8] dwords (b128 broadcast reads).
// Consumer: 16 samples x 4 float4 gathers + fma.
// ---------------------------------------------------------------------------
__global__ __launch_bounds__(256) void msda_kernel(
    const float* __restrict__ img_p, const float* __restrict__ qp,
    const float* __restrict__ refp, float* __restrict__ out)
{
    __shared__ int smem[16][32][8];   // 16 KB
    const int t  = threadIdx.x;
    const int t3 = t & 7;
    const int g  = t >> 3;                 // group slot in block (0..31)
    int gid = blockIdx.x * 32 + g;         // (b*NQ+n)*NH + h
    const bool valid = gid < NGRP;
    if (!valid) gid = NGRP - 1;            // clamp: keep all lanes live for barrier
    const int h  = gid & 7;
    const int bn = gid >> 3;
    const int b  = (bn >= NQ) ? 1 : 0;

    const float* q  = qp + (size_t)bn * 384 + h * 48;
    const float rx = refp[bn * 2 + 0];
    const float ry = refp[bn * 2 + 1];

    // producer: own samples s0=t3, s1=t3+8
    const float ox0 = q[t3 * 3 + 0],        oy0 = q[t3 * 3 + 1],        sc0 = q[t3 * 3 + 2];
    const float ox1 = q[(t3 + 8) * 3 + 0],  oy1 = q[(t3 + 8) * 3 + 1],  sc1 = q[(t3 + 8) * 3 + 2];

    float mx = fmaxf(sc0, sc1);
    mx = fmaxf(mx, __shfl_xor(mx, 1, 8));
    mx = fmaxf(mx, __shfl_xor(mx, 2, 8));
    mx = fmaxf(mx, __shfl_xor(mx, 4, 8));
    const float e0 = __expf(sc0 - mx);
    const float e1 = __expf(sc1 - mx);
    float sum = e0 + e1;
    sum += __shfl_xor(sum, 1, 8);
    sum += __shfl_xor(sum, 2, 8);
    sum += __shfl_xor(sum, 4, 8);
    const float inv = 1.0f / sum;

    #pragma unroll
    for (int which = 0; which < 2; ++which) {
        const int   s  = which ? (t3 + 8) : t3;
        const float ox = which ? ox1 : ox0;
        const float oy = which ? oy1 : oy0;
        const float aw = (which ? e1 : e0) * inv;
        const int l  = s >> 2;
        const int hh = LVL_H[l], ww = LVL_W[l], st = LVL_START[l];
        float x = (rx + ox) * (float)(ww - 1);
        float y = (ry + oy) * (float)(hh - 1);
        x = fminf(fmaxf(x, 0.f), (float)(ww - 1));
        y = fminf(fmaxf(y, 0.f), (float)(hh - 1));
        const float x0f = floorf(x), y0f = floorf(y);
        const int   x0 = (int)x0f,  y0 = (int)y0f;
        const float wx = x - x0f,   wy = y - y0f;
        const int dxb = (x0 < ww - 1) ? (NH * NCP * 4) : 0;        // +1 col, bytes
        const int dyb = (y0 < hh - 1) ? (ww * NH * NCP * 4) : 0;   // +1 row, bytes
        const int o00 = (st + y0 * ww + x0) * (NH * NCP * 4);      // pixel byte offset
        const float u0 = aw * (1.f - wx), u1 = aw * wx;
        int4 pa = make_int4(o00, dxb, dyb, __float_as_int(u0 * (1.f - wy)));
        int4 pb = make_int4(__float_as_int(u1 * (1.f - wy)),
                            __float_as_int(u0 * wy),
                            __float_as_int(u1 * wy), 0);
        *(int4*)&smem[s][g][0] = pa;
        *(int4*)&smem[s][g][4] = pb;
    }
    __syncthreads();

    // consumer: lane covers channels cp = t3*4 .. +3
    const char* base = (const char*)img_p
        + (((size_t)b * NQ * (NH * NCP) + h * NCP + t3 * 4) * 4);
    f32x4 acc = {0.f, 0.f, 0.f, 0.f};
    #pragma unroll
    for (int s = 0; s < 16; ++s) {
        const int4 pa = *(int4*)&smem[s][g][0];
        const int4 pb = *(int4*)&smem[s][g][4];
        const int o00 = pa.x;
        const int o01 = o00 + pa.y;
        const int o10 = o00 + pa.z;
        const int o11 = o10 + pa.y;
        const f32x4 v00 = *(const f32x4*)(base + o00);
        const f32x4 v01 = *(const f32x4*)(base + o01);
        const f32x4 v10 = *(const f32x4*)(base + o10);
        const f32x4 v11 = *(const f32x4*)(base + o11);
        acc += v00 * __int_as_float(pa.w);
        acc += v01 * __int_as_float(pb.x);
        acc += v10 * __int_as_float(pb.y);
        acc += v11 * __int_as_float(pb.z);
    }
    if (valid)
        *(f32x4*)(out + (size_t)bn * NHID + h * NCP + t3 * 4) = acc;
}

// ---------------------------------------------------------------------------
extern "C" void kernel_launch(void* const* d_in, const int* in_sizes, int n_in,
                              void* d_out, int out_size, void* d_ws, size_t ws_size,
                              hipStream_t stream) {
    const float* img     = (const float*)d_in[0];
    // d_in[1] = shapes (int32) -- hardcoded
    const float* queries = (const float*)d_in[2];
    const float* refp    = (const float*)d_in[3];
    const float* W_img   = (const float*)d_in[4];
    const float* b_img   = (const float*)d_in[5];
    const float* W_q     = (const float*)d_in[6];
    const float* b_q     = (const float*)d_in[7];
    const float* W_out   = (const float*)d_in[8];
    const float* b_out   = (const float*)d_in[9];
    float* out = (float*)d_out;

    // workspace (floats): img_p | qp | msda_out  (80.6 MB)
    float* ws = (float*)d_ws;
    float* img_p    = ws;
    float* qp       = img_p + (size_t)MROWS * NHID;
    float* msda_out = qp + (size_t)MROWS * 384;

    const int gRows = (MROWS + BM - 1) / BM;   // 176

    // 1. img_p = img @ W_img + b_img
    gemm_mfma_split<<<dim3(gRows, NHID / BN), 256, 0, stream>>>(
        img, W_img, b_img, img_p, MROWS, NHID, NEMB);
    // 2. qp = queries @ W_q + b_q
    gemm_mfma_split<<<dim3(gRows, 384 / BN), 256, 0, stream>>>(
        queries, W_q, b_q, qp, MROWS, 384, NEMB);
    // 3. fused softmax + sampling + weighted sum
    msda_kernel<<<(NGRP + 31) / 32, 256, 0, stream>>>(img_p, qp, refp, msda_out);
    // 4. out = msda_out @ W_out + b_out
    gemm_mfma_split<<<dim3(gRows, NEMB / BN), 256, 0, stream>>>(
        msda_out, W_out, b_out, out, MROWS, NEMB, NHID);
}